// Round 7
// baseline (741.500 us; speedup 1.0000x reference)
//
#include <hip/hip_runtime.h>
#include <cstdint>
#include <cstddef>

#define C_DIM 768
#define N_DIM 16384

typedef __attribute__((ext_vector_type(8))) short short8;   // 8 bf16 = 4 VGPRs
typedef __attribute__((ext_vector_type(4))) float f32x4;

__device__ __forceinline__ ushort f2bf(float f) {
    uint32_t u = __float_as_uint(f);
    uint32_t r = 0x7fffu + ((u >> 16) & 1u);   // round-to-nearest-even
    return (ushort)((u + r) >> 16);
}

__device__ __forceinline__ void async_ld16(const void* g, void* l) {
    __builtin_amdgcn_global_load_lds(
        (__attribute__((address_space(1))) void*)g,
        (__attribute__((address_space(3))) void*)l,
        16, 0, 0);
}

__device__ __forceinline__ f32x4 mfma16(short8 a, short8 b, f32x4 c) {
    return __builtin_amdgcn_mfma_f32_16x16x32_bf16(a, b, c, 0, 0, 0);
}

// ---------------------------------------------------------------------------
// Normalize columns of F (C_DIM x N_DIM) and write transposed bf16:
// T[i][c] = F[c][i] / max(||col_i||, eps).  blockIdx.y selects the input.
// (verified; unchanged)
// ---------------------------------------------------------------------------
__global__ __launch_bounds__(256) void norm_tr(const float* __restrict__ F0,
                                               ushort* __restrict__ T0,
                                               const float* __restrict__ F1,
                                               ushort* __restrict__ T1) {
    const float*  F = blockIdx.y ? F1 : F0;
    ushort*       T = blockIdx.y ? T1 : T0;
    const int i0 = blockIdx.x * 64;
    const int t  = threadIdx.x;
    const int tx = t & 63;
    const int ty = t >> 6;

    float ss = 0.f;
    for (int c = ty; c < C_DIM; c += 4) {
        float v = F[(size_t)c * N_DIM + i0 + tx];
        ss += v * v;
    }
    __shared__ float red[4][64];
    __shared__ float scale[64];
    red[ty][tx] = ss;
    __syncthreads();
    if (t < 64) {
        float s = red[0][t] + red[1][t] + red[2][t] + red[3][t];
        float n = sqrtf(s);
        scale[t] = 1.0f / fmaxf(n, 1e-12f);
    }
    __syncthreads();

    __shared__ float tile[64][65];
    const int i_l   = t >> 3;
    const int c_off = (t & 7) * 8;
    for (int c0 = 0; c0 < C_DIM; c0 += 64) {
        #pragma unroll
        for (int rr = 0; rr < 16; ++rr) {
            int c_l = rr * 4 + ty;
            tile[c_l][tx] = F[(size_t)(c0 + c_l) * N_DIM + i0 + tx] * scale[tx];
        }
        __syncthreads();
        #pragma unroll
        for (int half = 0; half < 2; ++half) {
            int il = i_l + half * 32;
            __align__(16) ushort pack[8];
            #pragma unroll
            for (int j = 0; j < 8; ++j)
                pack[j] = f2bf(tile[c_off + j][il]);
            *(uint4*)&T[(size_t)(i0 + il) * C_DIM + c0 + c_off] = *(const uint4*)pack;
        }
        __syncthreads();
    }
}

// ===========================================================================
// BIG PATH: m201-faithful 8-phase schedule, 256x256 tile, BK=64, 8 waves,
// DYNAMIC 128 KB LDS (E/O K-tile double-buffer), launched only if the
// runtime grants >=128KB dynamic shared memory (gate in kernel_launch).
//
// Layout per K-tile buffer (r4's refcheck-passed scheme, byte-identical):
//   A regions: R0 = a03 rows (dest 0 & 8192), R1 = a47 rows (4096 & 12288)
//   B regions: S0 = b01 frags (0 & 4096),     S1 = b23 frags (8192 & 12288)
//   chunk swizzle: content chunk (t&7)^((t>>3)&7) pre-applied on global src;
//   frag read aq = ((lane>>4) [+4]) ^ (lane&7).
//
// Iter j computes E=2j (phases 1-4: quadrants Q0..Q3) then O=2j+1 (p5-8).
// Stage rotation (2 gload_lds per phase, 16/iter):
//   p1: O.R1 | p2: E2.R0 | p3: E2.S0 | p4: E2.S1 |
//   p5: E2.R1| p6: O2.R0 | p7: O2.S0 | p8: O2.S1
// WAR audit: every stage targets a region whose last ds_read was >=2 phases
// earlier (O.R1@p1 after prev-p7 reads; E2.R0@p2 after p1; E2.S0@p3 after
// p1; E2.S1@p4 after p2; E2.R1@p5 after p3; O2.*@p6-8 after p5/p6 reads).
// vmcnt FIFO ledger (counted, never 0 in steady loop):
//   p4-end vmcnt(6): retires through p1's O.R1 -> O fully landed for p5-8.
//   p8-end vmcnt(6): retires through p5's E2.R1 -> next-E landed for p1-4.
//   Prologue: stage E0 (8) + O0.R0,S0,S1 (6); vmcnt(6) retires E0 exactly.
//   Tail iter (j=5): p1 stages O.R1 only; p4 vmcnt(0) drains; clean end.
// ===========================================================================
template<int N> __device__ __forceinline__ void wait_vmcnt() {
    if constexpr (N == 6)      asm volatile("s_waitcnt vmcnt(6)" ::: "memory");
    else if constexpr (N == 0) asm volatile("s_waitcnt vmcnt(0)" ::: "memory");
}

__device__ __forceinline__ void phase_head() {
    __builtin_amdgcn_s_barrier();
    asm volatile("s_waitcnt lgkmcnt(0)" ::: "memory");
    __builtin_amdgcn_sched_barrier(0);
    __builtin_amdgcn_s_setprio(1);
}

// stage helpers (2 x global_load_lds each)
__device__ __forceinline__ void st_r0(const ushort* agA, int ko, ushort* Aw, int ldst) {
    async_ld16(agA + ko,                 Aw + ldst);
    async_ld16(agA + ko + 128 * C_DIM,   Aw + 8192 + ldst);
}
__device__ __forceinline__ void st_r1(const ushort* agA, int ko, ushort* Aw, int ldst) {
    async_ld16(agA + ko + 64 * C_DIM,    Aw + 4096 + ldst);
    async_ld16(agA + ko + 192 * C_DIM,   Aw + 12288 + ldst);
}
__device__ __forceinline__ void st_s0(const ushort* bgB, int ko, ushort* Bw, int ldst) {
    async_ld16(bgB + ko,                 Bw + ldst);
    async_ld16(bgB + ko + 128 * C_DIM,   Bw + 4096 + ldst);
}
__device__ __forceinline__ void st_s1(const ushort* bgB, int ko, ushort* Bw, int ldst) {
    async_ld16(bgB + ko + 32 * C_DIM,    Bw + 8192 + ldst);
    async_ld16(bgB + ko + 160 * C_DIM,   Bw + 12288 + ldst);
}

template<bool TAIL>
__device__ __forceinline__ void big_iter(
    ushort* Ae, ushort* Be, ushort* Ao, ushort* Bo,
    const ushort* agA, const ushort* bgB,
    int kO, int kE2, int kO2,
    int ldst, int abase, int bbase, int aq0, int aq1,
    short8 (&a03)[4][2], short8 (&a47)[4][2],
    short8 (&b01)[2][2], short8 (&b23)[2][2],
    f32x4 (&acc)[8][4])
{
    // ---------------- p1: E.Q0 ----------------
    #pragma unroll
    for (int mt = 0; mt < 4; ++mt) {
        a03[mt][0] = *(const short8*)(Ae + abase + mt * 1024 + aq0);
        a03[mt][1] = *(const short8*)(Ae + abase + mt * 1024 + aq1);
    }
    #pragma unroll
    for (int nt = 0; nt < 2; ++nt) {
        b01[nt][0] = *(const short8*)(Be + bbase + nt * 1024 + aq0);
        b01[nt][1] = *(const short8*)(Be + bbase + nt * 1024 + aq1);
    }
    st_r1(agA, kO, Ao, ldst);               // this O's a47 region
    phase_head();
    #pragma unroll
    for (int mt = 0; mt < 4; ++mt)
        #pragma unroll
        for (int nt = 0; nt < 2; ++nt) {
            acc[mt][nt] = mfma16(a03[mt][0], b01[nt][0], acc[mt][nt]);
            acc[mt][nt] = mfma16(a03[mt][1], b01[nt][1], acc[mt][nt]);
        }
    __builtin_amdgcn_s_setprio(0);
    __builtin_amdgcn_s_barrier();

    // ---------------- p2: E.Q1 ----------------
    #pragma unroll
    for (int nt = 0; nt < 2; ++nt) {
        b23[nt][0] = *(const short8*)(Be + 8192 + bbase + nt * 1024 + aq0);
        b23[nt][1] = *(const short8*)(Be + 8192 + bbase + nt * 1024 + aq1);
    }
    if constexpr (!TAIL) st_r0(agA, kE2, Ae, ldst);
    phase_head();
    #pragma unroll
    for (int mt = 0; mt < 4; ++mt)
        #pragma unroll
        for (int nt = 0; nt < 2; ++nt) {
            acc[mt][2 + nt] = mfma16(a03[mt][0], b23[nt][0], acc[mt][2 + nt]);
            acc[mt][2 + nt] = mfma16(a03[mt][1], b23[nt][1], acc[mt][2 + nt]);
        }
    __builtin_amdgcn_s_setprio(0);
    __builtin_amdgcn_s_barrier();

    // ---------------- p3: E.Q2 ----------------
    #pragma unroll
    for (int mt = 0; mt < 4; ++mt) {
        a47[mt][0] = *(const short8*)(Ae + 4096 + abase + mt * 1024 + aq0);
        a47[mt][1] = *(const short8*)(Ae + 4096 + abase + mt * 1024 + aq1);
    }
    if constexpr (!TAIL) st_s0(bgB, kE2, Be, ldst);
    phase_head();
    #pragma unroll
    for (int mt = 0; mt < 4; ++mt)
        #pragma unroll
        for (int nt = 0; nt < 2; ++nt) {
            acc[4 + mt][nt] = mfma16(a47[mt][0], b01[nt][0], acc[4 + mt][nt]);
            acc[4 + mt][nt] = mfma16(a47[mt][1], b01[nt][1], acc[4 + mt][nt]);
        }
    __builtin_amdgcn_s_setprio(0);
    __builtin_amdgcn_s_barrier();

    // ---------------- p4: E.Q3 ----------------
    if constexpr (!TAIL) st_s1(bgB, kE2, Be, ldst);
    phase_head();
    #pragma unroll
    for (int mt = 0; mt < 4; ++mt)
        #pragma unroll
        for (int nt = 0; nt < 2; ++nt) {
            acc[4 + mt][2 + nt] = mfma16(a47[mt][0], b23[nt][0], acc[4 + mt][2 + nt]);
            acc[4 + mt][2 + nt] = mfma16(a47[mt][1], b23[nt][1], acc[4 + mt][2 + nt]);
        }
    __builtin_amdgcn_s_setprio(0);
    if constexpr (!TAIL) wait_vmcnt<6>(); else wait_vmcnt<0>();  // O certified
    __builtin_amdgcn_s_barrier();

    // ---------------- p5: O.Q0 ----------------
    #pragma unroll
    for (int mt = 0; mt < 4; ++mt) {
        a03[mt][0] = *(const short8*)(Ao + abase + mt * 1024 + aq0);
        a03[mt][1] = *(const short8*)(Ao + abase + mt * 1024 + aq1);
    }
    #pragma unroll
    for (int nt = 0; nt < 2; ++nt) {
        b01[nt][0] = *(const short8*)(Bo + bbase + nt * 1024 + aq0);
        b01[nt][1] = *(const short8*)(Bo + bbase + nt * 1024 + aq1);
    }
    if constexpr (!TAIL) st_r1(agA, kE2, Ae, ldst);
    phase_head();
    #pragma unroll
    for (int mt = 0; mt < 4; ++mt)
        #pragma unroll
        for (int nt = 0; nt < 2; ++nt) {
            acc[mt][nt] = mfma16(a03[mt][0], b01[nt][0], acc[mt][nt]);
            acc[mt][nt] = mfma16(a03[mt][1], b01[nt][1], acc[mt][nt]);
        }
    __builtin_amdgcn_s_setprio(0);
    __builtin_amdgcn_s_barrier();

    // ---------------- p6: O.Q1 ----------------
    #pragma unroll
    for (int nt = 0; nt < 2; ++nt) {
        b23[nt][0] = *(const short8*)(Bo + 8192 + bbase + nt * 1024 + aq0);
        b23[nt][1] = *(const short8*)(Bo + 8192 + bbase + nt * 1024 + aq1);
    }
    if constexpr (!TAIL) st_r0(agA, kO2, Ao, ldst);
    phase_head();
    #pragma unroll
    for (int mt = 0; mt < 4; ++mt)
        #pragma unroll
        for (int nt = 0; nt < 2; ++nt) {
            acc[mt][2 + nt] = mfma16(a03[mt][0], b23[nt][0], acc[mt][2 + nt]);
            acc[mt][2 + nt] = mfma16(a03[mt][1], b23[nt][1], acc[mt][2 + nt]);
        }
    __builtin_amdgcn_s_setprio(0);
    __builtin_amdgcn_s_barrier();

    // ---------------- p7: O.Q2 ----------------
    #pragma unroll
    for (int mt = 0; mt < 4; ++mt) {
        a47[mt][0] = *(const short8*)(Ao + 4096 + abase + mt * 1024 + aq0);
        a47[mt][1] = *(const short8*)(Ao + 4096 + abase + mt * 1024 + aq1);
    }
    if constexpr (!TAIL) st_s0(bgB, kO2, Bo, ldst);
    phase_head();
    #pragma unroll
    for (int mt = 0; mt < 4; ++mt)
        #pragma unroll
        for (int nt = 0; nt < 2; ++nt) {
            acc[4 + mt][nt] = mfma16(a47[mt][0], b01[nt][0], acc[4 + mt][nt]);
            acc[4 + mt][nt] = mfma16(a47[mt][1], b01[nt][1], acc[4 + mt][nt]);
        }
    __builtin_amdgcn_s_setprio(0);
    __builtin_amdgcn_s_barrier();

    // ---------------- p8: O.Q3 ----------------
    if constexpr (!TAIL) st_s1(bgB, kO2, Bo, ldst);
    phase_head();
    #pragma unroll
    for (int mt = 0; mt < 4; ++mt)
        #pragma unroll
        for (int nt = 0; nt < 2; ++nt) {
            acc[4 + mt][2 + nt] = mfma16(a47[mt][0], b23[nt][0], acc[4 + mt][2 + nt]);
            acc[4 + mt][2 + nt] = mfma16(a47[mt][1], b23[nt][1], acc[4 + mt][2 + nt]);
        }
    __builtin_amdgcn_s_setprio(0);
    if constexpr (!TAIL) wait_vmcnt<6>();           // next-E certified
    __builtin_amdgcn_s_barrier();
}

__global__ __launch_bounds__(512, 2) void gemm_rowmax_big(const ushort* __restrict__ A,
                                                          const ushort* __restrict__ B,
                                                          unsigned* __restrict__ rowkey) {
    extern __shared__ __align__(16) ushort lds[];   // 131072 B dynamic
    ushort* Ae = lds;                // E-tile A (32 KB = 16384 ushort)
    ushort* Ao = lds + 16384;        // O-tile A
    ushort* Be = lds + 32768;        // E-tile B
    ushort* Bo = lds + 49152;        // O-tile B

    const int t    = threadIdx.x;
    const int lane = t & 63;
    const int w    = t >> 6;          // 0..7
    const int wm   = w >> 2;          // 0..1  (128-row half)
    const int wn   = w & 3;           // 0..3  (64-col quarter)

    const int bid   = blockIdx.x;
    const int xcd   = bid & 7;
    const int local = bid >> 3;                       // 0..511
    const int m0    = (local >> 3) * 256;             // 64 m-tiles
    const int n0    = (xcd * 8 + (local & 7)) * 256;  // 64 n-tiles

    f32x4 acc[8][4];
    #pragma unroll
    for (int i = 0; i < 8; ++i)
        #pragma unroll
        for (int j = 0; j < 4; ++j)
            acc[i][j] = (f32x4){0.f, 0.f, 0.f, 0.f};

    // staging sources (pre-swizzled global; r4-verified)
    const int srow = t >> 3;                           // 0..63
    const int schk = ((t & 7) ^ (srow & 7)) * 8;       // element offset
    const ushort* agA = A + (size_t)(m0 + srow) * C_DIM + schk;
    const int brow = ((t >> 8) & 1) * 64 + (srow & 31);
    const ushort* bgB = B + (size_t)(n0 + brow) * C_DIM + schk;
    const int ldst = t * 8;

    // fragment read addressing (r4-verified)
    const int aq0   = ((lane >> 4) ^ (lane & 7)) * 8;
    const int aq1   = (((lane >> 4) + 4) ^ (lane & 7)) * 8;
    const int abase = wm * 8192 + (lane & 15) * 64;
    const int bbase = wn * 2048 + (lane & 15) * 64;

    short8 a03[4][2], a47[4][2], b01[2][2], b23[2][2];

    // prologue: E0 complete (8 loads) + O0.R0,S0,S1 (6 loads)
    st_r0(agA, 0, Ae, ldst);  st_s0(bgB, 0, Be, ldst);
    st_s1(bgB, 0, Be, ldst);  st_r1(agA, 0, Ae, ldst);
    st_r0(agA, 64, Ao, ldst); st_s0(bgB, 64, Bo, ldst); st_s1(bgB, 64, Bo, ldst);
    wait_vmcnt<6>();          // retires exactly E0's 8; O0's 6 in flight
    __builtin_amdgcn_s_barrier();

    #pragma unroll 1
    for (int j = 0; j < 5; ++j)
        big_iter<false>(Ae, Be, Ao, Bo, agA, bgB,
                        (2 * j + 1) * 64, (2 * j + 2) * 64, (2 * j + 3) * 64,
                        ldst, abase, bbase, aq0, aq1,
                        a03, a47, b01, b23, acc);
    big_iter<true>(Ae, Be, Ao, Bo, agA, bgB,
                   11 * 64, 0, 0,
                   ldst, abase, bbase, aq0, aq1,
                   a03, a47, b01, b23, acc);

    // epilogue (r4-verified): C/D col = lane&15, row = (lane>>4)*4 + reg
    #pragma unroll
    for (int mt = 0; mt < 8; ++mt) {
        #pragma unroll
        for (int reg = 0; reg < 4; ++reg) {
            float v = fmaxf(fmaxf(acc[mt][0][reg], acc[mt][1][reg]),
                            fmaxf(acc[mt][2][reg], acc[mt][3][reg]));
            #pragma unroll
            for (int off = 1; off < 16; off <<= 1)
                v = fmaxf(v, __shfl_xor(v, off, 64));
            if ((lane & 15) == 0) {
                int m = m0 + wm * 128 + mt * 16 + (lane >> 4) * 4 + reg;
                unsigned u = __float_as_uint(v);
                u = (u & 0x80000000u) ? ~u : (u | 0x80000000u);
                atomicMax(&rowkey[m], u);
            }
        }
    }
}

// ===========================================================================
// FALLBACK: r2 kernel verbatim (measured 555 us, passed) — 128x256 tile,
// 512 thr / 8 waves, 48 KB dbuf, counted vmcnt(3), XOR swizzle.
// ===========================================================================
__global__ __launch_bounds__(512) void gemm_rowmax_fb(const ushort* __restrict__ A,
                                                      const ushort* __restrict__ B,
                                                      unsigned* __restrict__ rowkey) {
    __shared__ __align__(16) ushort As[2][128 * 32];   // 16 KB
    __shared__ __align__(16) ushort Bs[2][256 * 32];   // 32 KB

    const int t    = threadIdx.x;
    const int lane = t & 63;
    const int w    = t >> 6;
    const int wm   = w >> 2;
    const int wn   = w & 3;

    const int bid   = blockIdx.x;
    const int xcd   = bid & 7;
    const int local = bid >> 3;
    const int m0    = (local >> 3) * 128;
    const int n0    = (xcd * 8 + (local & 7)) * 256;

    f32x4 acc[4][4];
    #pragma unroll
    for (int i = 0; i < 4; ++i)
        #pragma unroll
        for (int j = 0; j < 4; ++j)
            acc[i][j] = (f32x4){0.f, 0.f, 0.f, 0.f};

    const int kq = ((t & 3) ^ ((t >> 3) & 3)) * 8;
    const ushort* ag  = A + (size_t)(m0 + (t >> 2)) * C_DIM + kq;
    const ushort* bg0 = B + (size_t)(n0 + (t >> 2)) * C_DIM + kq;
    const ushort* bg1 = bg0 + (size_t)128 * C_DIM;
    const int lda = t * 8;
    const int ldb0 = t * 8, ldb1 = 128 * 32 + t * 8;

    const int qp    = ((lane >> 4) ^ ((lane >> 1) & 3)) * 8;
    const int a_off = (wm * 64 + (lane & 15)) * 32 + qp;
    const int b_off = (wn * 64 + (lane & 15)) * 32 + qp;

    async_ld16(ag,  As[0] + lda);
    async_ld16(bg0, Bs[0] + ldb0);
    async_ld16(bg1, Bs[0] + ldb1);

    int buf = 0;
    for (int k0 = 0; k0 < C_DIM - 32; k0 += 32) {
        const int kn = k0 + 32, nb = buf ^ 1;
        async_ld16(ag + kn,  As[nb] + lda);
        async_ld16(bg0 + kn, Bs[nb] + ldb0);
        async_ld16(bg1 + kn, Bs[nb] + ldb1);

        asm volatile("s_waitcnt vmcnt(3)" ::: "memory");
        __builtin_amdgcn_s_barrier();

        const ushort* Ab = As[buf];
        const ushort* Bb = Bs[buf];
        short8 af[4], bfr[4];
        #pragma unroll
        for (int mt = 0; mt < 4; ++mt)
            af[mt] = *(const short8*)(Ab + a_off + mt * 16 * 32);
        #pragma unroll
        for (int nt = 0; nt < 4; ++nt)
            bfr[nt] = *(const short8*)(Bb + b_off + nt * 16 * 32);

        __builtin_amdgcn_s_setprio(1);
        #pragma unroll
        for (int mt = 0; mt < 4; ++mt)
            #pragma unroll
            for (int nt = 0; nt < 4; ++nt)
                acc[mt][nt] = mfma16(af[mt], bfr[nt], acc[mt][nt]);
        __builtin_amdgcn_s_setprio(0);

        asm volatile("s_waitcnt lgkmcnt(0)" ::: "memory");
        __builtin_amdgcn_s_barrier();
        buf ^= 1;
    }
    {
        asm volatile("s_waitcnt vmcnt(0)" ::: "memory");
        __builtin_amdgcn_s_barrier();
        const ushort* Ab = As[buf];
        const ushort* Bb = Bs[buf];
        short8 af[4], bfr[4];
        #pragma unroll
        for (int mt = 0; mt < 4; ++mt)
            af[mt] = *(const short8*)(Ab + a_off + mt * 16 * 32);
        #pragma unroll
        for (int nt = 0; nt < 4; ++nt)
            bfr[nt] = *(const short8*)(Bb + b_off + nt * 16 * 32);
        __builtin_amdgcn_s_setprio(1);
        #pragma unroll
        for (int mt = 0; mt < 4; ++mt)
            #pragma unroll
            for (int nt = 0; nt < 4; ++nt)
                acc[mt][nt] = mfma16(af[mt], bfr[nt], acc[mt][nt]);
        __builtin_amdgcn_s_setprio(0);
    }

    #pragma unroll
    for (int mt = 0; mt < 4; ++mt) {
        #pragma unroll
        for (int reg = 0; reg < 4; ++reg) {
            float v = fmaxf(fmaxf(acc[mt][0][reg], acc[mt][1][reg]),
                            fmaxf(acc[mt][2][reg], acc[mt][3][reg]));
            #pragma unroll
            for (int off = 1; off < 16; off <<= 1)
                v = fmaxf(v, __shfl_xor(v, off, 64));
            if ((lane & 15) == 0) {
                int m = m0 + wm * 64 + mt * 16 + (lane >> 4) * 4 + reg;
                unsigned u = __float_as_uint(v);
                u = (u & 0x80000000u) ? ~u : (u | 0x80000000u);
                atomicMax(&rowkey[m], u);
            }
        }
    }
}

// ---------------------------------------------------------------------------
// Final: loss = 1 - mean(rowmax)
// ---------------------------------------------------------------------------
__global__ __launch_bounds__(1024) void finalize(const unsigned* __restrict__ rowkey,
                                                 float* __restrict__ out) {
    const int t = threadIdx.x;
    float s = 0.f;
    for (int i = t; i < N_DIM; i += 1024) {
        unsigned u = rowkey[i];
        float f = (u & 0x80000000u) ? __uint_as_float(u ^ 0x80000000u)
                                    : __uint_as_float(~u);
        s += f;
    }
    #pragma unroll
    for (int off = 32; off >= 1; off >>= 1)
        s += __shfl_down(s, off, 64);
    __shared__ float part[16];
    if ((t & 63) == 0) part[t >> 6] = s;
    __syncthreads();
    if (t == 0) {
        float tot = 0.f;
        #pragma unroll
        for (int i = 0; i < 16; ++i) tot += part[i];
        out[0] = 1.0f - tot * (1.0f / (float)N_DIM);
    }
}

extern "C" void kernel_launch(void* const* d_in, const int* in_sizes, int n_in,
                              void* d_out, int out_size, void* d_ws, size_t ws_size,
                              hipStream_t stream) {
    const float* F_r = (const float*)d_in[0];
    const float* F_s = (const float*)d_in[1];

    ushort*   Rt     = (ushort*)d_ws;                       // 16384 x 768 bf16
    ushort*   St     = Rt + (size_t)N_DIM * C_DIM;          // 16384 x 768 bf16
    unsigned* rowkey = (unsigned*)(St + (size_t)N_DIM * C_DIM);  // 16384 u32
    float*    out    = (float*)d_out;

    // One-time gate: can this runtime give gemm_rowmax_big 128 KB dynamic LDS?
    // Probe via attribute set + VERIFIED read-back; never issue a failing
    // launch.  Host-side attribute calls are legal during graph capture.
    static int big_ok = -1;
    if (big_ok < 0) {
        (void)hipFuncSetAttribute((const void*)gemm_rowmax_big,
                                  hipFuncAttributeMaxDynamicSharedMemorySize,
                                  131072);
        hipFuncAttributes fa{};
        int ok = 0;
        if (hipFuncGetAttributes(&fa, (const void*)gemm_rowmax_big) == hipSuccess &&
            fa.maxDynamicSharedSizeBytes >= 131072)
            ok = 1;
        (void)hipGetLastError();   // clear any sticky probe error
        big_ok = ok;
    }

    hipLaunchKernelGGL(norm_tr, dim3(N_DIM / 64, 2), dim3(256), 0, stream,
                       F_r, Rt, F_s, St);
    hipMemsetAsync(rowkey, 0, N_DIM * sizeof(unsigned), stream);
    if (big_ok) {
        hipLaunchKernelGGL(gemm_rowmax_big,
                           dim3((N_DIM / 256) * (N_DIM / 256)), dim3(512),
                           131072, stream, Rt, St, rowkey);
    } else {
        hipLaunchKernelGGL(gemm_rowmax_fb,
                           dim3((N_DIM / 128) * (N_DIM / 256)), dim3(512),
                           0, stream, Rt, St, rowkey);
    }
    hipLaunchKernelGGL(finalize, dim3(1), dim3(1024), 0, stream, rowkey, out);
}